// Round 7
// baseline (251.403 us; speedup 1.0000x reference)
//
#include <hip/hip_runtime.h>
#include <stdint.h>

// ---------------------------------------------------------------------------
// SelfAttn: B=4, W=H=64, C=256, C2=128, N=W*H=4096.
// pq = raw q buffer viewed [128,4096]  (Q_rows[n,c] = q_flat[c*4096+n])
// pv = raw v buffer viewed [256,4096]  (natural layout == PV B-operand layout)
// energy = Qrm @ Krm^T (K=128), softmax over keys (fixed ref m=0),
// O[n,c] = sum_m P[n,m] V[m,c];  final[b,c*4096+n] = gamma*O/l + x.
//
// R6 post-mortem: V B-frags direct from global = 32 lanes x 8KB-strided rows
// per instruction -> VMEM request amplification (attn 91->131us). The R5 Vs
// LDS round-trip is a LAYOUT TRANSFORM (coalesced global in, per-lane frags
// out), not waste. R7: R5 attn verbatim, occupancy 2 -> 3 blocks/CU
// (LDS 46KB*3=138<=160; regs 104+64=168<=170=512/3).
// ---------------------------------------------------------------------------

typedef __attribute__((ext_vector_type(8)))  short short8;   // 8 x bf16
typedef __attribute__((ext_vector_type(4)))  float f32x4;
typedef __attribute__((ext_vector_type(16))) float f32x16;
typedef __attribute__((ext_vector_type(4)))  unsigned short u16x4;

#define MFMA16 __builtin_amdgcn_mfma_f32_16x16x32_bf16
#define MFMA32 __builtin_amdgcn_mfma_f32_32x32x16_bf16

__device__ __forceinline__ unsigned short f2bf(float f) {
    union { float f; uint32_t u; } v; v.f = f;
    return (unsigned short)((v.u + 0x8000u) >> 16);    // round-half-up (2 VALU)
}
__device__ __forceinline__ float bf2f(unsigned short h) {
    union { uint32_t u; float f; } v; v.u = ((uint32_t)h) << 16;
    return v.f;
}

// --- K1: Wt[512][256] bf16 (transposed, fused qkv) + bias[512] f32 ---------
__global__ void prep_w(const float* __restrict__ Wq, const float* __restrict__ bq,
                       const float* __restrict__ Wk, const float* __restrict__ bk,
                       const float* __restrict__ Wv, const float* __restrict__ bv,
                       unsigned short* __restrict__ Wt, float* __restrict__ bias) {
    int g = blockIdx.x * 256 + threadIdx.x;
    int c = g & 255, d = g >> 8;
    float val;
    if (d < 128)      val = Wq[c * 128 + d];
    else if (d < 256) val = Wk[c * 128 + (d - 128)];
    else              val = Wv[c * 256 + (d - 256)];
    Wt[d * 256 + c] = f2bf(val);
    if (g < 512) {
        float bb;
        if (g < 128)      bb = bq[g];
        else if (g < 256) bb = bk[g - 128];
        else              bb = bv[g - 256];
        bias[g] = bb;
    }
}

// --- K2: fused QKV projection. 512 blocks ----------------------------------
__global__ __launch_bounds__(256) void proj(
        const float* __restrict__ x, const unsigned short* __restrict__ Wt,
        const float* __restrict__ bias,
        unsigned short* __restrict__ Qrm, unsigned short* __restrict__ Krm,
        unsigned short* __restrict__ Vbf) {
    __shared__ unsigned short T[128 * 136];
    int bid = blockIdx.x;
    int tid = threadIdx.x;
    int wave = tid >> 6, lane = tid & 63;
    int l16 = lane & 15, quad = lane >> 4;

    int kind, b, a, vh = 0;
    if (bid < 256) { kind = bid >> 7; int s = bid & 127; b = s >> 5; a = s & 31; }
    else           { kind = 2; int s = bid - 256; vh = s >> 7; b = (s >> 5) & 3; a = s & 31; }

    short8 af[2][8];
    #pragma unroll
    for (int g = 0; g < 2; ++g) {
        int p_local = wave * 32 + g * 16 + l16;
        int pix = (kind == 2) ? (b * 4096 + a * 128 + p_local)
                              : (b * 4096 + a + 32 * p_local);
        const float* xr = x + (size_t)pix * 256;
        #pragma unroll
        for (int kk = 0; kk < 8; ++kk) {
            f32x4 u0 = *(const f32x4*)(xr + kk * 32 + quad * 8);
            f32x4 u1 = *(const f32x4*)(xr + kk * 32 + quad * 8 + 4);
            short8 h;
            h[0] = (short)f2bf(u0[0]); h[1] = (short)f2bf(u0[1]);
            h[2] = (short)f2bf(u0[2]); h[3] = (short)f2bf(u0[3]);
            h[4] = (short)f2bf(u1[0]); h[5] = (short)f2bf(u1[1]);
            h[6] = (short)f2bf(u1[2]); h[7] = (short)f2bf(u1[3]);
            af[g][kk] = h;
        }
    }

    if (kind < 2) {
        int dbase = kind * 128;
        unsigned short* out = kind ? Krm : Qrm;
        #pragma unroll 1
        for (int dt = 0; dt < 8; ++dt) {
            int d = dbase + dt * 16 + l16;
            float bval = bias[d];
            f32x4 acc0 = {0.f,0.f,0.f,0.f}, acc1 = {0.f,0.f,0.f,0.f};
            #pragma unroll
            for (int kk = 0; kk < 8; ++kk) {
                short8 wrow = *(const short8*)(Wt + d * 256 + kk * 32 + quad * 8);
                acc0 = MFMA16(af[0][kk], wrow, acc0, 0, 0, 0);
                acc1 = MFMA16(af[1][kk], wrow, acc1, 0, 0, 0);
            }
            #pragma unroll
            for (int g = 0; g < 2; ++g) {
                f32x4 acc = g ? acc1 : acc0;
                u16x4 pk;
                #pragma unroll
                for (int reg = 0; reg < 4; ++reg) pk[reg] = f2bf(acc[reg] + bval);
                *(u16x4*)(T + (dt * 16 + l16) * 136 + wave * 32 + g * 16 + quad * 4) = pk;
            }
        }
        __syncthreads();
        unsigned short* ob = out + (b << 19) + a * 128 * 128;
        #pragma unroll
        for (int it = 0; it < 8; ++it) {
            int ci = it * 256 + tid;
            int row = ci >> 4, cj = ci & 15;
            *(short8*)(ob + row * 128 + cj * 8) = *(const short8*)(T + row * 136 + cj * 8);
        }
    } else {
        #pragma unroll 1
        for (int dt = 0; dt < 8; ++dt) {
            int d = 256 + vh * 128 + dt * 16 + l16;
            f32x4 acc0 = {0.f,0.f,0.f,0.f}, acc1 = {0.f,0.f,0.f,0.f};
            #pragma unroll
            for (int kk = 0; kk < 8; ++kk) {
                short8 wrow = *(const short8*)(Wt + d * 256 + kk * 32 + quad * 8);
                acc0 = MFMA16(wrow, af[0][kk], acc0, 0, 0, 0);   // A=W, B=x -> D^T
                acc1 = MFMA16(wrow, af[1][kk], acc1, 0, 0, 0);
            }
            int dvl = dt * 16 + quad * 4;
            f32x4 bv4 = *(const f32x4*)(bias + 256 + vh * 128 + dvl);
            #pragma unroll
            for (int g = 0; g < 2; ++g) {
                f32x4 acc = g ? acc1 : acc0;
                u16x4 pk;
                #pragma unroll
                for (int reg = 0; reg < 4; ++reg) pk[reg] = f2bf(acc[reg] + bv4[reg]);
                int p_local = wave * 32 + g * 16 + l16;
                *(u16x4*)(T + p_local * 136 + dvl) = pk;
            }
        }
        __syncthreads();
        #pragma unroll
        for (int it = 0; it < 8; ++it) {
            int cid = it * 256 + tid;
            int c_local = cid >> 8, w = cid & 255;
            int p_local = c_local * 16 + (w >> 4);
            int m = (w >> 4) * 256 + vh * 128 + (w & 15) * 8;
            *(short8*)(Vbf + (b << 20) + (size_t)(a * 8 + c_local) * 4096 + m)
                = *(const short8*)(T + p_local * 136 + (w & 15) * 8);
        }
    }
}

// --- K3: flash attention. grid 512 = 64 qtiles x (4 b x 2 ks) --------------
// 64 queries/block, 64-key tiles (32 tiles), 32x32x16 MFMA. R5 structure:
// QK: wave (mt,nt): S^T[mt][nt] with K prefetched in registers.
// V: coalesced global->vreg prefetch (1 tile ahead) -> Vs LDS (layout
// transform) -> per-lane b128 B-frags. 2 barriers/tile. 3 blocks/CU.
__global__ __launch_bounds__(256, 3) void attn(
        const unsigned short* __restrict__ Qrm, const unsigned short* __restrict__ Krm,
        const unsigned short* __restrict__ Vbf, unsigned short* __restrict__ Opart,
        float* __restrict__ Lpart) {
    __shared__ unsigned short Vs[256 * 72];            // V tile [c][m=64 +pad]
    __shared__ unsigned short Ps[64 * 72];             // P [q=64][m=64 +pad]

    int bid = blockIdx.x;
    int comb = bid & 7, qt = bid >> 3;                 // same (b,ks) -> same XCD
    int b = comb >> 1, ks = comb & 1;
    int tid = threadIdx.x, wave = tid >> 6, lane = tid & 63;
    int l32 = lane & 31, half = lane >> 5;
    int mt = wave & 1, nt = wave >> 1;

    const unsigned short* Qb = Qrm + (b << 19);
    const unsigned short* Kb = Krm + (b << 19);
    const unsigned short* Vb = Vbf + (b << 20);

    int q0 = qt * 64;

    short8 qf[8];                                      // B=Q for wave's 32 queries
    {
        const unsigned short* qrow = Qb + (q0 + nt * 32 + l32) * 128 + half * 8;
        #pragma unroll
        for (int kk = 0; kk < 8; ++kk) qf[kk] = *(const short8*)(qrow + kk * 16);
    }

    f32x16 O[2][2];                                    // [qtile][ctile]
    #pragma unroll
    for (int i = 0; i < 2; ++i)
        #pragma unroll
        for (int j = 0; j < 2; ++j)
            #pragma unroll
            for (int r = 0; r < 16; ++r) O[i][j][r] = 0.f;
    float l_run = 0.f;

    const int m_base = ks * 2048;
    int vrow = tid >> 3, vch = tid & 7;

    short8 vreg[8];                                    // V staging prefetch (tile 0)
    #pragma unroll
    for (int i = 0; i < 8; ++i)
        vreg[i] = *(const short8*)(Vb + (size_t)(vrow + i * 32) * 4096 + m_base + vch * 8);
    short8 kf[8];                                      // A=K frags (tile 0)
    {
        const unsigned short* krow = Kb + (m_base + mt * 32 + l32) * 128 + half * 8;
        #pragma unroll
        for (int kk = 0; kk < 8; ++kk) kf[kk] = *(const short8*)(krow + kk * 16);
    }

    #pragma unroll 1
    for (int kt = 0; kt < 32; ++kt) {
        __syncthreads();                               // A: prev readers done; prefetch landed
        #pragma unroll
        for (int i = 0; i < 8; ++i)
            *(short8*)(Vs + (vrow + i * 32) * 72 + vch * 8) = vreg[i];

        // S^T[m][n]: A=kf (keys), B=qf (queries); col n = l32 (query),
        // row m (within mtile) = (r&3)+8*(r>>2)+4*half.
        f32x16 S;
        #pragma unroll
        for (int r = 0; r < 16; ++r) S[r] = 0.f;
        #pragma unroll
        for (int kk = 0; kk < 8; ++kk) S = MFMA32(kf[kk], qf[kk], S, 0, 0, 0);

        // fixed-ref softmax (m=0): p = exp(S); l += sum p; pack -> Ps
        float rs = 0.f;
        #pragma unroll
        for (int g = 0; g < 4; ++g) {
            u16x4 pk;
            #pragma unroll
            for (int i = 0; i < 4; ++i) {
                float p = __expf(S[g * 4 + i]);
                rs += p;
                pk[i] = f2bf(p);
            }
            // P[q][m]: q = nt*32+l32, m = mt*32 + g*8 + half*4 + i
            *(u16x4*)(Ps + (nt * 32 + l32) * 72 + mt * 32 + g * 8 + half * 4) = pk;
        }
        rs += __shfl_xor(rs, 32);                      // add half-partner m's
        l_run += rs;

        __syncthreads();                               // B: Vs + Ps ready

        if (kt < 31) {                                 // prefetch next tile during PV
            int m1 = m_base + (kt + 1) * 64;
            #pragma unroll
            for (int i = 0; i < 8; ++i)
                vreg[i] = *(const short8*)(Vb + (size_t)(vrow + i * 32) * 4096 + m1 + vch * 8);
            const unsigned short* krow = Kb + (m1 + mt * 32 + l32) * 128 + half * 8;
            #pragma unroll
            for (int kk = 0; kk < 8; ++kk) kf[kk] = *(const short8*)(krow + kk * 16);
        }

        // PV: A=P rows q, B=V cols c; wave ctiles {2w,2w+1}, qtiles {0,1}
        #pragma unroll
        for (int k2 = 0; k2 < 4; ++k2) {
            short8 pa0 = *(const short8*)(Ps + (l32) * 72 + k2 * 16 + half * 8);
            short8 pa1 = *(const short8*)(Ps + (32 + l32) * 72 + k2 * 16 + half * 8);
            #pragma unroll
            for (int c2 = 0; c2 < 2; ++c2) {
                short8 vb = *(const short8*)(Vs + ((wave * 2 + c2) * 32 + l32) * 72 + k2 * 16 + half * 8);
                O[0][c2] = MFMA32(pa0, vb, O[0][c2], 0, 0, 0);
                O[1][c2] = MFMA32(pa1, vb, O[1][c2], 0, 0, 0);
            }
        }
    }

    // epilogue: unnormalized O + per-query l partials
    unsigned short* Op = Opart + ((size_t)(ks * 4 + b) << 20);
    #pragma unroll
    for (int q2 = 0; q2 < 2; ++q2)
        #pragma unroll
        for (int c2 = 0; c2 < 2; ++c2) {
            int c = (wave * 2 + c2) * 32 + l32;
            #pragma unroll
            for (int r = 0; r < 16; ++r) {
                int n = q0 + q2 * 32 + (r & 3) + 8 * (r >> 2) + 4 * half;
                Op[(size_t)n * 256 + c] = f2bf(O[q2][c2][r]);
            }
        }
    if (half == 0) {
        int n = q0 + nt * 32 + l32;
        Lpart[((ks * 2 + mt) * 4 + b) * 4096 + n] = l_run;
    }
}

// --- K4: merge 2 key-splits (4 l-partials), gamma*O/l + x, transpose -------
__global__ __launch_bounds__(256) void merge_out(
        const unsigned short* __restrict__ Opart, const float* __restrict__ Lpart,
        const float* __restrict__ x, const float* __restrict__ gamma,
        float* __restrict__ out) {
    __shared__ float tile[64][65];
    __shared__ float wsm[64];
    int b  = blockIdx.x >> 6;
    int n0 = (blockIdx.x & 63) << 6;
    int tid = threadIdx.x;
    float g = gamma[0];
    if (tid < 64) {
        int n = n0 + tid;
        float L = 0.f;
        #pragma unroll
        for (int s = 0; s < 4; ++s) L += Lpart[(s * 4 + b) * 4096 + n];
        wsm[tid] = g / L;
    }
    __syncthreads();
    int cl  = tid & 63, nl4 = tid >> 6;
    int nl  = tid & 63, cl4 = tid >> 6;
    for (int cc = 0; cc < 4; ++cc) {
        for (int i = 0; i < 16; ++i) {
            int n = n0 + i * 4 + nl4;
            int c = (cc << 6) + cl;
            float On = 0.f;
            #pragma unroll
            for (int s = 0; s < 2; ++s)
                On += bf2f(Opart[((size_t)(s * 4 + b) << 20) + (size_t)n * 256 + c]);
            tile[cl][i * 4 + nl4] = On * wsm[i * 4 + nl4];
        }
        __syncthreads();
        for (int j = 0; j < 16; ++j) {
            int c = (cc << 6) + j * 4 + cl4;
            int idx = (b << 20) + c * 4096 + n0 + nl;
            out[idx] = tile[j * 4 + cl4][nl] + x[idx];
        }
        __syncthreads();
    }
}

// ---------------------------------------------------------------------------
extern "C" void kernel_launch(void* const* d_in, const int* in_sizes, int n_in,
                              void* d_out, int out_size, void* d_ws, size_t ws_size,
                              hipStream_t stream) {
    const float* x     = (const float*)d_in[0];
    const float* Wq    = (const float*)d_in[1];
    const float* bq    = (const float*)d_in[2];
    const float* Wk    = (const float*)d_in[3];
    const float* bk    = (const float*)d_in[4];
    const float* Wv    = (const float*)d_in[5];
    const float* bv    = (const float*)d_in[6];
    const float* gamma = (const float*)d_in[7];
    float* out = (float*)d_out;

    if (ws_size < 34080768u) return;   // need ~33 MB scratch

    char* ws = (char*)d_ws;
    unsigned short* Wt    = (unsigned short*)(ws);             //    262,144 B
    float*          bias  = (float*)        (ws +   262144);   //      2,048 B
    unsigned short* Qrm   = (unsigned short*)(ws +   264192);  //  4,194,304 B
    unsigned short* Krm   = (unsigned short*)(ws +  4458496);  //  4,194,304 B
    unsigned short* Vbf   = (unsigned short*)(ws +  8652800);  //  8,388,608 B
    unsigned short* Opart = (unsigned short*)(ws + 17041408);  // 16,777,216 B
    float*          Lpart = (float*)        (ws + 33818624);   //    262,144 B

    prep_w   <<<512, 256, 0, stream>>>(Wq, bq, Wk, bk, Wv, bv, Wt, bias);
    proj     <<<512, 256, 0, stream>>>(x, Wt, bias, Qrm, Krm, Vbf);
    attn     <<<512, 256, 0, stream>>>(Qrm, Krm, Vbf, Opart, Lpart);
    merge_out<<<256, 256, 0, stream>>>(Opart, Lpart, x, gamma, out);
}

// Round 8
// 206.692 us; speedup vs baseline: 1.2163x; 1.2163x over previous
//
#include <hip/hip_runtime.h>
#include <stdint.h>

// ---------------------------------------------------------------------------
// SelfAttn: B=4, W=H=64, C=256, C2=128, N=W*H=4096.
// pq = raw q buffer viewed [128,4096]  (Q_rows[n,c] = q_flat[c*4096+n])
// pv = raw v buffer viewed [256,4096]  (natural layout == PV B-operand layout)
// energy = Qrm @ Krm^T (K=128), softmax over keys (fixed ref m=0),
// O[n,c] = sum_m P[n,m] V[m,c];  final[b,c*4096+n] = gamma*O/l + x.
//
// R7 post-mortem: launch_bounds(256,3) forced VGPR 104->84 -> spill (WRITE
// 16.6->31.5MB) with NO occupancy gain. 2 waves/SIMD + R5 register set is
// the budget. R8: keep (256,2); V tile is already per-wave partitioned in PV
// -> each wave stages its own 64-row Vs region (no barrier needed for Vs);
// Ps double-buffered -> ONE barrier per kt; prefetches issued post-barrier
// so the conservative vmcnt(0) pre-barrier drain sees only landed loads.
// ---------------------------------------------------------------------------

typedef __attribute__((ext_vector_type(8)))  short short8;   // 8 x bf16
typedef __attribute__((ext_vector_type(4)))  float f32x4;
typedef __attribute__((ext_vector_type(16))) float f32x16;
typedef __attribute__((ext_vector_type(4)))  unsigned short u16x4;

#define MFMA16 __builtin_amdgcn_mfma_f32_16x16x32_bf16
#define MFMA32 __builtin_amdgcn_mfma_f32_32x32x16_bf16

__device__ __forceinline__ unsigned short f2bf(float f) {
    union { float f; uint32_t u; } v; v.f = f;
    return (unsigned short)((v.u + 0x8000u) >> 16);    // round-half-up
}
__device__ __forceinline__ float bf2f(unsigned short h) {
    union { uint32_t u; float f; } v; v.u = ((uint32_t)h) << 16;
    return v.f;
}

// --- K1: Wt[512][256] bf16 (transposed, fused qkv) + bias[512] f32 ---------
__global__ void prep_w(const float* __restrict__ Wq, const float* __restrict__ bq,
                       const float* __restrict__ Wk, const float* __restrict__ bk,
                       const float* __restrict__ Wv, const float* __restrict__ bv,
                       unsigned short* __restrict__ Wt, float* __restrict__ bias) {
    int g = blockIdx.x * 256 + threadIdx.x;
    int c = g & 255, d = g >> 8;
    float val;
    if (d < 128)      val = Wq[c * 128 + d];
    else if (d < 256) val = Wk[c * 128 + (d - 128)];
    else              val = Wv[c * 256 + (d - 256)];
    Wt[d * 256 + c] = f2bf(val);
    if (g < 512) {
        float bb;
        if (g < 128)      bb = bq[g];
        else if (g < 256) bb = bk[g - 128];
        else              bb = bv[g - 256];
        bias[g] = bb;
    }
}

// --- K2: fused QKV projection. 384 blocks:
//   [0,128)   QK-kind: block(b,a) pixels {a+32*cc}, d 0..255 (Q then K halves,
//             shared A-frags) -> Qrm/Krm contiguous tiles via LDS transpose
//   [128,384) V-kind: block(b,vh,a), dv vh*128..+127 -> Vbf (swapped-operand
//             D^T + LDS transpose -> coalesced natural-layout writes)
__global__ __launch_bounds__(256) void proj(
        const float* __restrict__ x, const unsigned short* __restrict__ Wt,
        const float* __restrict__ bias,
        unsigned short* __restrict__ Qrm, unsigned short* __restrict__ Krm,
        unsigned short* __restrict__ Vbf) {
    __shared__ unsigned short T[128 * 136];
    int bid = blockIdx.x;
    int tid = threadIdx.x;
    int wave = tid >> 6, lane = tid & 63;
    int l16 = lane & 15, quad = lane >> 4;

    int kind, b, a, vh = 0;
    if (bid < 128) { kind = 0; b = bid >> 5; a = bid & 31; }
    else           { kind = 1; int s = bid - 128; vh = s >> 7; b = (s >> 5) & 3; a = s & 31; }

    short8 af[2][8];
    #pragma unroll
    for (int g = 0; g < 2; ++g) {
        int p_local = wave * 32 + g * 16 + l16;
        int pix = kind ? (b * 4096 + a * 128 + p_local)
                       : (b * 4096 + a + 32 * p_local);
        const float* xr = x + (size_t)pix * 256;
        #pragma unroll
        for (int kk = 0; kk < 8; ++kk) {
            f32x4 u0 = *(const f32x4*)(xr + kk * 32 + quad * 8);
            f32x4 u1 = *(const f32x4*)(xr + kk * 32 + quad * 8 + 4);
            short8 h;
            h[0] = (short)f2bf(u0[0]); h[1] = (short)f2bf(u0[1]);
            h[2] = (short)f2bf(u0[2]); h[3] = (short)f2bf(u0[3]);
            h[4] = (short)f2bf(u1[0]); h[5] = (short)f2bf(u1[1]);
            h[6] = (short)f2bf(u1[2]); h[7] = (short)f2bf(u1[3]);
            af[g][kk] = h;
        }
    }

    if (kind == 0) {
        #pragma unroll 1
        for (int k2 = 0; k2 < 2; ++k2) {               // Q half then K half
            int dbase = k2 * 128;
            unsigned short* outp = k2 ? Krm : Qrm;
            #pragma unroll 1
            for (int dt = 0; dt < 8; ++dt) {
                int d = dbase + dt * 16 + l16;
                float bval = bias[d];
                f32x4 acc0 = {0.f,0.f,0.f,0.f}, acc1 = {0.f,0.f,0.f,0.f};
                #pragma unroll
                for (int kk = 0; kk < 8; ++kk) {
                    short8 wrow = *(const short8*)(Wt + d * 256 + kk * 32 + quad * 8);
                    acc0 = MFMA16(af[0][kk], wrow, acc0, 0, 0, 0);
                    acc1 = MFMA16(af[1][kk], wrow, acc1, 0, 0, 0);
                }
                #pragma unroll
                for (int g = 0; g < 2; ++g) {
                    f32x4 acc = g ? acc1 : acc0;
                    u16x4 pk;
                    #pragma unroll
                    for (int reg = 0; reg < 4; ++reg) pk[reg] = f2bf(acc[reg] + bval);
                    *(u16x4*)(T + (dt * 16 + l16) * 136 + wave * 32 + g * 16 + quad * 4) = pk;
                }
            }
            __syncthreads();
            unsigned short* ob = outp + (b << 19) + a * 128 * 128;
            #pragma unroll
            for (int it = 0; it < 8; ++it) {
                int ci = it * 256 + tid;
                int row = ci >> 4, cj = ci & 15;
                *(short8*)(ob + row * 128 + cj * 8) = *(const short8*)(T + row * 136 + cj * 8);
            }
            __syncthreads();
        }
    } else {
        #pragma unroll 1
        for (int dt = 0; dt < 8; ++dt) {
            int d = 256 + vh * 128 + dt * 16 + l16;
            f32x4 acc0 = {0.f,0.f,0.f,0.f}, acc1 = {0.f,0.f,0.f,0.f};
            #pragma unroll
            for (int kk = 0; kk < 8; ++kk) {
                short8 wrow = *(const short8*)(Wt + d * 256 + kk * 32 + quad * 8);
                acc0 = MFMA16(wrow, af[0][kk], acc0, 0, 0, 0);   // A=W, B=x -> D^T
                acc1 = MFMA16(wrow, af[1][kk], acc1, 0, 0, 0);
            }
            int dvl = dt * 16 + quad * 4;
            f32x4 bv4 = *(const f32x4*)(bias + 256 + vh * 128 + dvl);
            #pragma unroll
            for (int g = 0; g < 2; ++g) {
                f32x4 acc = g ? acc1 : acc0;
                u16x4 pk;
                #pragma unroll
                for (int reg = 0; reg < 4; ++reg) pk[reg] = f2bf(acc[reg] + bv4[reg]);
                int p_local = wave * 32 + g * 16 + l16;
                *(u16x4*)(T + p_local * 136 + dvl) = pk;
            }
        }
        __syncthreads();
        #pragma unroll
        for (int it = 0; it < 8; ++it) {
            int cid = it * 256 + tid;
            int c_local = cid >> 8, w = cid & 255;
            int p_local = c_local * 16 + (w >> 4);
            int m = (w >> 4) * 256 + vh * 128 + (w & 15) * 8;
            *(short8*)(Vbf + (b << 20) + (size_t)(a * 8 + c_local) * 4096 + m)
                = *(const short8*)(T + p_local * 136 + (w & 15) * 8);
        }
    }
}

// --- K3: flash attention. grid 512 = 64 qtiles x (4 b x 2 ks) --------------
// 64 queries/block, 64-key tiles (32 tiles), 32x32x16 MFMA.
// Vs: per-wave-private 64-row region (wave stages exactly the c-rows it
// reads) -> no barrier for V. Ps double-buffered -> 1 barrier per kt.
// kf/vreg prefetch issued post-barrier (drained loads only at barrier).
__global__ __launch_bounds__(256, 2) void attn(
        const unsigned short* __restrict__ Qrm, const unsigned short* __restrict__ Krm,
        const unsigned short* __restrict__ Vbf, unsigned short* __restrict__ Opart,
        float* __restrict__ Lpart) {
    __shared__ unsigned short Vs[256 * 72];            // 4 x per-wave [64 c][64 m +pad]
    __shared__ unsigned short Ps[2 * 64 * 72];         // P [q=64][m=64 +pad], x2

    int bid = blockIdx.x;
    int comb = bid & 7, qt = bid >> 3;                 // same (b,ks) -> same XCD
    int b = comb >> 1, ks = comb & 1;
    int tid = threadIdx.x, wave = tid >> 6, lane = tid & 63;
    int l32 = lane & 31, half = lane >> 5;
    int mt = wave & 1, nt = wave >> 1;

    const unsigned short* Qb = Qrm + (b << 19);
    const unsigned short* Kb = Krm + (b << 19);
    const unsigned short* Vb = Vbf + (b << 20);
    unsigned short* VsW = Vs + wave * 64 * 72;         // wave-private region

    int q0 = qt * 64;

    short8 qf[8];                                      // B=Q for wave's 32 queries
    {
        const unsigned short* qrow = Qb + (q0 + nt * 32 + l32) * 128 + half * 8;
        #pragma unroll
        for (int kk = 0; kk < 8; ++kk) qf[kk] = *(const short8*)(qrow + kk * 16);
    }

    f32x16 O[2][2];                                    // [qtile][ctile]
    #pragma unroll
    for (int i = 0; i < 2; ++i)
        #pragma unroll
        for (int j = 0; j < 2; ++j)
            #pragma unroll
            for (int r = 0; r < 16; ++r) O[i][j][r] = 0.f;
    float l_run = 0.f;

    const int m_base = ks * 2048;
    int vrow = lane >> 3, vch = lane & 7;              // within-wave staging coords

    // tile-0: load V rows (wave's own c range), stage, load K frags
    short8 vreg[8];
    #pragma unroll
    for (int i = 0; i < 8; ++i)
        vreg[i] = *(const short8*)(Vb + (size_t)(wave * 64 + vrow + i * 8) * 4096
                                   + m_base + vch * 8);
    short8 kf[8];
    {
        const unsigned short* krow = Kb + (m_base + mt * 32 + l32) * 128 + half * 8;
        #pragma unroll
        for (int kk = 0; kk < 8; ++kk) kf[kk] = *(const short8*)(krow + kk * 16);
    }
    #pragma unroll
    for (int i = 0; i < 8; ++i)
        *(short8*)(VsW + (vrow + i * 8) * 72 + vch * 8) = vreg[i];

    #pragma unroll 1
    for (int kt = 0; kt < 32; ++kt) {
        unsigned short* Pb = Ps + (kt & 1) * (64 * 72);

        // S^T[m][n]: A=kf (keys), B=qf (queries); col n = l32 (query),
        // row m (within mtile) = (r&3)+8*(r>>2)+4*half.
        f32x16 S;
        #pragma unroll
        for (int r = 0; r < 16; ++r) S[r] = 0.f;
        #pragma unroll
        for (int kk = 0; kk < 8; ++kk) S = MFMA32(kf[kk], qf[kk], S, 0, 0, 0);

        // fixed-ref softmax (m=0): p = exp(S); l += sum p; pack -> Ps[buf]
        float rs = 0.f;
        #pragma unroll
        for (int g = 0; g < 4; ++g) {
            u16x4 pk;
            #pragma unroll
            for (int i = 0; i < 4; ++i) {
                float p = __expf(S[g * 4 + i]);
                rs += p;
                pk[i] = f2bf(p);
            }
            // P[q][m]: q = nt*32+l32, m = mt*32 + g*8 + half*4 + i
            *(u16x4*)(Pb + (nt * 32 + l32) * 72 + mt * 32 + g * 8 + half * 4) = pk;
        }
        rs += __shfl_xor(rs, 32);                      // add half-partner m's
        l_run += rs;

        __syncthreads();                               // Ps[buf] ready (only barrier)

        if (kt < 31) {                                 // prefetch kt+1 (post-drain)
            int m1 = m_base + (kt + 1) * 64;
            #pragma unroll
            for (int i = 0; i < 8; ++i)
                vreg[i] = *(const short8*)(Vb + (size_t)(wave * 64 + vrow + i * 8) * 4096
                                           + m1 + vch * 8);
            const unsigned short* krow = Kb + (m1 + mt * 32 + l32) * 128 + half * 8;
            #pragma unroll
            for (int kk = 0; kk < 8; ++kk) kf[kk] = *(const short8*)(krow + kk * 16);
        }

        // PV: A=P rows q, B=V from wave-private Vs; ctiles {2w,2w+1}
        #pragma unroll
        for (int k2 = 0; k2 < 4; ++k2) {
            short8 pa0 = *(const short8*)(Pb + (l32) * 72 + k2 * 16 + half * 8);
            short8 pa1 = *(const short8*)(Pb + (32 + l32) * 72 + k2 * 16 + half * 8);
            #pragma unroll
            for (int c2 = 0; c2 < 2; ++c2) {
                short8 vb = *(const short8*)(VsW + (c2 * 32 + l32) * 72 + k2 * 16 + half * 8);
                O[0][c2] = MFMA32(pa0, vb, O[0][c2], 0, 0, 0);
                O[1][c2] = MFMA32(pa1, vb, O[1][c2], 0, 0, 0);
            }
        }

        if (kt < 31) {                                 // stage V(kt+1): own region,
            #pragma unroll                             // after own reads (wave-ordered)
            for (int i = 0; i < 8; ++i)
                *(short8*)(VsW + (vrow + i * 8) * 72 + vch * 8) = vreg[i];
        }
    }

    // epilogue: unnormalized O + per-query l partials
    unsigned short* Op = Opart + ((size_t)(ks * 4 + b) << 20);
    #pragma unroll
    for (int q2 = 0; q2 < 2; ++q2)
        #pragma unroll
        for (int c2 = 0; c2 < 2; ++c2) {
            int c = (wave * 2 + c2) * 32 + l32;
            #pragma unroll
            for (int r = 0; r < 16; ++r) {
                int n = q0 + q2 * 32 + (r & 3) + 8 * (r >> 2) + 4 * half;
                Op[(size_t)n * 256 + c] = f2bf(O[q2][c2][r]);
            }
        }
    if (half == 0) {
        int n = q0 + nt * 32 + l32;
        Lpart[((ks * 2 + mt) * 4 + b) * 4096 + n] = l_run;
    }
}

// --- K4: merge 2 key-splits (4 l-partials), gamma*O/l + x, transpose -------
__global__ __launch_bounds__(256) void merge_out(
        const unsigned short* __restrict__ Opart, const float* __restrict__ Lpart,
        const float* __restrict__ x, const float* __restrict__ gamma,
        float* __restrict__ out) {
    __shared__ float tile[64][65];
    __shared__ float wsm[64];
    int b  = blockIdx.x >> 6;
    int n0 = (blockIdx.x & 63) << 6;
    int tid = threadIdx.x;
    float g = gamma[0];
    if (tid < 64) {
        int n = n0 + tid;
        float L = 0.f;
        #pragma unroll
        for (int s = 0; s < 4; ++s) L += Lpart[(s * 4 + b) * 4096 + n];
        wsm[tid] = g / L;
    }
    __syncthreads();
    int cl  = tid & 63, nl4 = tid >> 6;
    int nl  = tid & 63, cl4 = tid >> 6;
    for (int cc = 0; cc < 4; ++cc) {
        for (int i = 0; i < 16; ++i) {
            int n = n0 + i * 4 + nl4;
            int c = (cc << 6) + cl;
            float On = 0.f;
            #pragma unroll
            for (int s = 0; s < 2; ++s)
                On += bf2f(Opart[((size_t)(s * 4 + b) << 20) + (size_t)n * 256 + c]);
            tile[cl][i * 4 + nl4] = On * wsm[i * 4 + nl4];
        }
        __syncthreads();
        for (int j = 0; j < 16; ++j) {
            int c = (cc << 6) + j * 4 + cl4;
            int idx = (b << 20) + c * 4096 + n0 + nl;
            out[idx] = tile[j * 4 + cl4][nl] + x[idx];
        }
        __syncthreads();
    }
}

// ---------------------------------------------------------------------------
extern "C" void kernel_launch(void* const* d_in, const int* in_sizes, int n_in,
                              void* d_out, int out_size, void* d_ws, size_t ws_size,
                              hipStream_t stream) {
    const float* x     = (const float*)d_in[0];
    const float* Wq    = (const float*)d_in[1];
    const float* bq    = (const float*)d_in[2];
    const float* Wk    = (const float*)d_in[3];
    const float* bk    = (const float*)d_in[4];
    const float* Wv    = (const float*)d_in[5];
    const float* bv    = (const float*)d_in[6];
    const float* gamma = (const float*)d_in[7];
    float* out = (float*)d_out;

    if (ws_size < 34080768u) return;   // need ~33 MB scratch

    char* ws = (char*)d_ws;
    unsigned short* Wt    = (unsigned short*)(ws);             //    262,144 B
    float*          bias  = (float*)        (ws +   262144);   //      2,048 B
    unsigned short* Qrm   = (unsigned short*)(ws +   264192);  //  4,194,304 B
    unsigned short* Krm   = (unsigned short*)(ws +  4458496);  //  4,194,304 B
    unsigned short* Vbf   = (unsigned short*)(ws +  8652800);  //  8,388,608 B
    unsigned short* Opart = (unsigned short*)(ws + 17041408);  // 16,777,216 B
    float*          Lpart = (float*)        (ws + 33818624);   //    262,144 B

    prep_w   <<<512, 256, 0, stream>>>(Wq, bq, Wk, bk, Wv, bv, Wt, bias);
    proj     <<<384, 256, 0, stream>>>(x, Wt, bias, Qrm, Krm, Vbf);
    attn     <<<512, 256, 0, stream>>>(Qrm, Krm, Vbf, Opart, Lpart);
    merge_out<<<256, 256, 0, stream>>>(Opart, Lpart, x, gamma, out);
}

// Round 9
// 194.857 us; speedup vs baseline: 1.2902x; 1.0607x over previous
//
#include <hip/hip_runtime.h>
#include <hip/hip_bf16.h>
#include <stdint.h>

// ---------------------------------------------------------------------------
// SelfAttn: B=4, W=H=64, C=256, C2=128, N=W*H=4096.
// pq = raw q buffer viewed [128,4096]  (Q_rows[n,c] = q_flat[c*4096+n])
// pv = raw v buffer viewed [256,4096]  (natural layout == PV B-operand layout)
// energy = Qrm @ Krm^T (K=128), softmax over keys (fixed ref m=0),
// O[n,c] = sum_m P[n,m] V[m,c];  final[b,c*4096+n] = gamma*O/l + x.
//
// R8 post-mortem: 1-barrier vs 2-barrier attn = neutral (barriers not the
// limiter); proj QK-fusion (384 blocks) = load imbalance regression. R9:
// revert to measured-best R5 attn + R5 512-block proj; cut VALU with packed
// hardware bf16 converts (v_cvt_pk_bf16_f32 via __float22bfloat162_rn) and
// defer the softmax cross-half shfl to the epilogue.
// ---------------------------------------------------------------------------

typedef __attribute__((ext_vector_type(8)))  short short8;   // 8 x bf16
typedef __attribute__((ext_vector_type(4)))  float f32x4;
typedef __attribute__((ext_vector_type(16))) float f32x16;
typedef __attribute__((ext_vector_type(4)))  unsigned short u16x4;

#define MFMA16 __builtin_amdgcn_mfma_f32_16x16x32_bf16
#define MFMA32 __builtin_amdgcn_mfma_f32_32x32x16_bf16

__device__ __forceinline__ unsigned short f2bf(float f) {
    union { float f; uint32_t u; } v; v.f = f;
    return (unsigned short)((v.u + 0x8000u) >> 16);    // round-half-up
}
__device__ __forceinline__ float bf2f(unsigned short h) {
    union { uint32_t u; float f; } v; v.u = ((uint32_t)h) << 16;
    return v.f;
}
// packed f32x2 -> bf16x2 (v_cvt_pk_bf16_f32, RNE)
__device__ __forceinline__ uint32_t pkbf(float a, float b) {
    union { __hip_bfloat162 h; uint32_t u; } v;
    v.h = __float22bfloat162_rn(float2{a, b});
    return v.u;
}

// --- K1: Wt[512][256] bf16 (transposed, fused qkv) + bias[512] f32 ---------
__global__ void prep_w(const float* __restrict__ Wq, const float* __restrict__ bq,
                       const float* __restrict__ Wk, const float* __restrict__ bk,
                       const float* __restrict__ Wv, const float* __restrict__ bv,
                       unsigned short* __restrict__ Wt, float* __restrict__ bias) {
    int g = blockIdx.x * 256 + threadIdx.x;
    int c = g & 255, d = g >> 8;
    float val;
    if (d < 128)      val = Wq[c * 128 + d];
    else if (d < 256) val = Wk[c * 128 + (d - 128)];
    else              val = Wv[c * 256 + (d - 256)];
    Wt[d * 256 + c] = f2bf(val);
    if (g < 512) {
        float bb;
        if (g < 128)      bb = bq[g];
        else if (g < 256) bb = bk[g - 128];
        else              bb = bv[g - 256];
        bias[g] = bb;
    }
}

// --- K2: fused QKV projection. 512 uniform blocks (R5 structure):
//   [0,128)   Q-kind: block(b,a) pixels {a+32*cc}, d 0..127   -> Qrm tiles
//   [128,256) K-kind: same pixels, d 128..255                 -> Krm tiles
//   [256,512) V-kind: block(b,vh,a), dv vh*128..+127          -> Vbf natural
__global__ __launch_bounds__(256) void proj(
        const float* __restrict__ x, const unsigned short* __restrict__ Wt,
        const float* __restrict__ bias,
        unsigned short* __restrict__ Qrm, unsigned short* __restrict__ Krm,
        unsigned short* __restrict__ Vbf) {
    __shared__ unsigned short T[128 * 136];
    int bid = blockIdx.x;
    int tid = threadIdx.x;
    int wave = tid >> 6, lane = tid & 63;
    int l16 = lane & 15, quad = lane >> 4;

    int kind, b, a, vh = 0;
    if (bid < 256) { kind = bid >> 7; int s = bid & 127; b = s >> 5; a = s & 31; }
    else           { kind = 2; int s = bid - 256; vh = s >> 7; b = (s >> 5) & 3; a = s & 31; }

    short8 af[2][8];
    #pragma unroll
    for (int g = 0; g < 2; ++g) {
        int p_local = wave * 32 + g * 16 + l16;
        int pix = (kind == 2) ? (b * 4096 + a * 128 + p_local)
                              : (b * 4096 + a + 32 * p_local);
        const float* xr = x + (size_t)pix * 256;
        #pragma unroll
        for (int kk = 0; kk < 8; ++kk) {
            f32x4 u0 = *(const f32x4*)(xr + kk * 32 + quad * 8);
            f32x4 u1 = *(const f32x4*)(xr + kk * 32 + quad * 8 + 4);
            union { short8 s; uint32_t u[4]; } h;
            h.u[0] = pkbf(u0[0], u0[1]); h.u[1] = pkbf(u0[2], u0[3]);
            h.u[2] = pkbf(u1[0], u1[1]); h.u[3] = pkbf(u1[2], u1[3]);
            af[g][kk] = h.s;
        }
    }

    if (kind < 2) {
        int dbase = kind * 128;
        unsigned short* out = kind ? Krm : Qrm;
        #pragma unroll 1
        for (int dt = 0; dt < 8; ++dt) {
            int d = dbase + dt * 16 + l16;
            float bval = bias[d];
            f32x4 acc0 = {0.f,0.f,0.f,0.f}, acc1 = {0.f,0.f,0.f,0.f};
            #pragma unroll
            for (int kk = 0; kk < 8; ++kk) {
                short8 wrow = *(const short8*)(Wt + d * 256 + kk * 32 + quad * 8);
                acc0 = MFMA16(af[0][kk], wrow, acc0, 0, 0, 0);
                acc1 = MFMA16(af[1][kk], wrow, acc1, 0, 0, 0);
            }
            #pragma unroll
            for (int g = 0; g < 2; ++g) {
                f32x4 acc = g ? acc1 : acc0;
                union { u16x4 v; uint32_t u[2]; } pk;
                pk.u[0] = pkbf(acc[0] + bval, acc[1] + bval);
                pk.u[1] = pkbf(acc[2] + bval, acc[3] + bval);
                *(u16x4*)(T + (dt * 16 + l16) * 136 + wave * 32 + g * 16 + quad * 4) = pk.v;
            }
        }
        __syncthreads();
        unsigned short* ob = out + (b << 19) + a * 128 * 128;
        #pragma unroll
        for (int it = 0; it < 8; ++it) {
            int ci = it * 256 + tid;
            int row = ci >> 4, cj = ci & 15;
            *(short8*)(ob + row * 128 + cj * 8) = *(const short8*)(T + row * 136 + cj * 8);
        }
    } else {
        #pragma unroll 1
        for (int dt = 0; dt < 8; ++dt) {
            int d = 256 + vh * 128 + dt * 16 + l16;
            f32x4 acc0 = {0.f,0.f,0.f,0.f}, acc1 = {0.f,0.f,0.f,0.f};
            #pragma unroll
            for (int kk = 0; kk < 8; ++kk) {
                short8 wrow = *(const short8*)(Wt + d * 256 + kk * 32 + quad * 8);
                acc0 = MFMA16(wrow, af[0][kk], acc0, 0, 0, 0);   // A=W, B=x -> D^T
                acc1 = MFMA16(wrow, af[1][kk], acc1, 0, 0, 0);
            }
            int dvl = dt * 16 + quad * 4;
            f32x4 bv4 = *(const f32x4*)(bias + 256 + vh * 128 + dvl);
            #pragma unroll
            for (int g = 0; g < 2; ++g) {
                f32x4 acc = g ? acc1 : acc0;
                union { u16x4 v; uint32_t u[2]; } pk;
                pk.u[0] = pkbf(acc[0] + bv4[0], acc[1] + bv4[1]);
                pk.u[1] = pkbf(acc[2] + bv4[2], acc[3] + bv4[3]);
                int p_local = wave * 32 + g * 16 + l16;
                *(u16x4*)(T + p_local * 136 + dvl) = pk.v;
            }
        }
        __syncthreads();
        #pragma unroll
        for (int it = 0; it < 8; ++it) {
            int cid = it * 256 + tid;
            int c_local = cid >> 8, w = cid & 255;
            int p_local = c_local * 16 + (w >> 4);
            int m = (w >> 4) * 256 + vh * 128 + (w & 15) * 8;
            *(short8*)(Vbf + (b << 20) + (size_t)(a * 8 + c_local) * 4096 + m)
                = *(const short8*)(T + p_local * 136 + (w & 15) * 8);
        }
    }
}

// --- K3: flash attention (R5 structure, measured best). --------------------
// grid 512 = 64 qtiles x (4 b x 2 ks); 64 queries/block, 64-key tiles,
// 32x32x16 MFMA. Shared Vs staging via vreg prefetch, Ps single-buffer,
// 2 barriers/kt. Packed bf16 cvt in softmax; cross-half l-sum deferred.
__global__ __launch_bounds__(256, 2) void attn(
        const unsigned short* __restrict__ Qrm, const unsigned short* __restrict__ Krm,
        const unsigned short* __restrict__ Vbf, unsigned short* __restrict__ Opart,
        float* __restrict__ Lpart) {
    __shared__ unsigned short Vs[256 * 72];            // V tile [c][m=64 +pad]
    __shared__ unsigned short Ps[64 * 72];             // P [q=64][m=64 +pad]

    int bid = blockIdx.x;
    int comb = bid & 7, qt = bid >> 3;                 // same (b,ks) -> same XCD
    int b = comb >> 1, ks = comb & 1;
    int tid = threadIdx.x, wave = tid >> 6, lane = tid & 63;
    int l32 = lane & 31, half = lane >> 5;
    int mt = wave & 1, nt = wave >> 1;

    const unsigned short* Qb = Qrm + (b << 19);
    const unsigned short* Kb = Krm + (b << 19);
    const unsigned short* Vb = Vbf + (b << 20);

    int q0 = qt * 64;

    short8 qf[8];                                      // B=Q for wave's 32 queries
    {
        const unsigned short* qrow = Qb + (q0 + nt * 32 + l32) * 128 + half * 8;
        #pragma unroll
        for (int kk = 0; kk < 8; ++kk) qf[kk] = *(const short8*)(qrow + kk * 16);
    }

    f32x16 O[2][2];                                    // [qtile][ctile]
    #pragma unroll
    for (int i = 0; i < 2; ++i)
        #pragma unroll
        for (int j = 0; j < 2; ++j)
            #pragma unroll
            for (int r = 0; r < 16; ++r) O[i][j][r] = 0.f;
    float l_run = 0.f;                                 // own-half partial only

    const int m_base = ks * 2048;
    int vrow = tid >> 3, vch = tid & 7;

    short8 vreg[8];                                    // V staging prefetch (tile 0)
    #pragma unroll
    for (int i = 0; i < 8; ++i)
        vreg[i] = *(const short8*)(Vb + (size_t)(vrow + i * 32) * 4096 + m_base + vch * 8);
    short8 kf[8];                                      // A=K frags (tile 0)
    {
        const unsigned short* krow = Kb + (m_base + mt * 32 + l32) * 128 + half * 8;
        #pragma unroll
        for (int kk = 0; kk < 8; ++kk) kf[kk] = *(const short8*)(krow + kk * 16);
    }

    #pragma unroll 1
    for (int kt = 0; kt < 32; ++kt) {
        __syncthreads();                               // A: prev readers done; prefetch landed
        #pragma unroll
        for (int i = 0; i < 8; ++i)
            *(short8*)(Vs + (vrow + i * 32) * 72 + vch * 8) = vreg[i];

        // S^T[m][n]: A=kf (keys), B=qf (queries); col n = l32 (query),
        // row m (within mtile) = (r&3)+8*(r>>2)+4*half.
        f32x16 S;
        #pragma unroll
        for (int r = 0; r < 16; ++r) S[r] = 0.f;
        #pragma unroll
        for (int kk = 0; kk < 8; ++kk) S = MFMA32(kf[kk], qf[kk], S, 0, 0, 0);

        // fixed-ref softmax (m=0): p = exp(S); l += sum p; pack -> Ps
        #pragma unroll
        for (int g = 0; g < 4; ++g) {
            float p0 = __expf(S[g * 4 + 0]), p1 = __expf(S[g * 4 + 1]);
            float p2 = __expf(S[g * 4 + 2]), p3 = __expf(S[g * 4 + 3]);
            l_run += (p0 + p1) + (p2 + p3);
            union { u16x4 v; uint32_t u[2]; } pk;
            pk.u[0] = pkbf(p0, p1); pk.u[1] = pkbf(p2, p3);
            // P[q][m]: q = nt*32+l32, m = mt*32 + g*8 + half*4 + i
            *(u16x4*)(Ps + (nt * 32 + l32) * 72 + mt * 32 + g * 8 + half * 4) = pk.v;
        }

        __syncthreads();                               // B: Vs + Ps ready

        if (kt < 31) {                                 // prefetch next tile during PV
            int m1 = m_base + (kt + 1) * 64;
            #pragma unroll
            for (int i = 0; i < 8; ++i)
                vreg[i] = *(const short8*)(Vb + (size_t)(vrow + i * 32) * 4096 + m1 + vch * 8);
            const unsigned short* krow = Kb + (m1 + mt * 32 + l32) * 128 + half * 8;
            #pragma unroll
            for (int kk = 0; kk < 8; ++kk) kf[kk] = *(const short8*)(krow + kk * 16);
        }

        // PV: A=P rows q, B=V cols c; wave ctiles {2w,2w+1}, qtiles {0,1}
        #pragma unroll
        for (int k2 = 0; k2 < 4; ++k2) {
            short8 pa0 = *(const short8*)(Ps + (l32) * 72 + k2 * 16 + half * 8);
            short8 pa1 = *(const short8*)(Ps + (32 + l32) * 72 + k2 * 16 + half * 8);
            #pragma unroll
            for (int c2 = 0; c2 < 2; ++c2) {
                short8 vb = *(const short8*)(Vs + ((wave * 2 + c2) * 32 + l32) * 72 + k2 * 16 + half * 8);
                O[0][c2] = MFMA32(pa0, vb, O[0][c2], 0, 0, 0);
                O[1][c2] = MFMA32(pa1, vb, O[1][c2], 0, 0, 0);
            }
        }
    }

    // epilogue: unnormalized O + per-query l partials (cross-half sum here)
    l_run += __shfl_xor(l_run, 32);
    unsigned short* Op = Opart + ((size_t)(ks * 4 + b) << 20);
    #pragma unroll
    for (int q2 = 0; q2 < 2; ++q2)
        #pragma unroll
        for (int c2 = 0; c2 < 2; ++c2) {
            int c = (wave * 2 + c2) * 32 + l32;
            #pragma unroll
            for (int r = 0; r < 16; ++r) {
                int n = q0 + q2 * 32 + (r & 3) + 8 * (r >> 2) + 4 * half;
                Op[(size_t)n * 256 + c] = f2bf(O[q2][c2][r]);
            }
        }
    if (half == 0) {
        int n = q0 + nt * 32 + l32;
        Lpart[((ks * 2 + mt) * 4 + b) * 4096 + n] = l_run;
    }
}

// --- K4: merge 2 key-splits (4 l-partials), gamma*O/l + x, transpose -------
__global__ __launch_bounds__(256) void merge_out(
        const unsigned short* __restrict__ Opart, const float* __restrict__ Lpart,
        const float* __restrict__ x, const float* __restrict__ gamma,
        float* __restrict__ out) {
    __shared__ float tile[64][65];
    __shared__ float wsm[64];
    int b  = blockIdx.x >> 6;
    int n0 = (blockIdx.x & 63) << 6;
    int tid = threadIdx.x;
    float g = gamma[0];
    if (tid < 64) {
        int n = n0 + tid;
        float L = 0.f;
        #pragma unroll
        for (int s = 0; s < 4; ++s) L += Lpart[(s * 4 + b) * 4096 + n];
        wsm[tid] = g / L;
    }
    __syncthreads();
    int cl  = tid & 63, nl4 = tid >> 6;
    int nl  = tid & 63, cl4 = tid >> 6;
    for (int cc = 0; cc < 4; ++cc) {
        for (int i = 0; i < 16; ++i) {
            int n = n0 + i * 4 + nl4;
            int c = (cc << 6) + cl;
            float On = 0.f;
            #pragma unroll
            for (int s = 0; s < 2; ++s)
                On += bf2f(Opart[((size_t)(s * 4 + b) << 20) + (size_t)n * 256 + c]);
            tile[cl][i * 4 + nl4] = On * wsm[i * 4 + nl4];
        }
        __syncthreads();
        for (int j = 0; j < 16; ++j) {
            int c = (cc << 6) + j * 4 + cl4;
            int idx = (b << 20) + c * 4096 + n0 + nl;
            out[idx] = tile[j * 4 + cl4][nl] + x[idx];
        }
        __syncthreads();
    }
}

// ---------------------------------------------------------------------------
extern "C" void kernel_launch(void* const* d_in, const int* in_sizes, int n_in,
                              void* d_out, int out_size, void* d_ws, size_t ws_size,
                              hipStream_t stream) {
    const float* x     = (const float*)d_in[0];
    const float* Wq    = (const float*)d_in[1];
    const float* bq    = (const float*)d_in[2];
    const float* Wk    = (const float*)d_in[3];
    const float* bk    = (const float*)d_in[4];
    const float* Wv    = (const float*)d_in[5];
    const float* bv    = (const float*)d_in[6];
    const float* gamma = (const float*)d_in[7];
    float* out = (float*)d_out;

    if (ws_size < 34080768u) return;   // need ~33 MB scratch

    char* ws = (char*)d_ws;
    unsigned short* Wt    = (unsigned short*)(ws);             //    262,144 B
    float*          bias  = (float*)        (ws +   262144);   //      2,048 B
    unsigned short* Qrm   = (unsigned short*)(ws +   264192);  //  4,194,304 B
    unsigned short* Krm   = (unsigned short*)(ws +  4458496);  //  4,194,304 B
    unsigned short* Vbf   = (unsigned short*)(ws +  8652800);  //  8,388,608 B
    unsigned short* Opart = (unsigned short*)(ws + 17041408);  // 16,777,216 B
    float*          Lpart = (float*)        (ws + 33818624);   //    262,144 B

    prep_w   <<<512, 256, 0, stream>>>(Wq, bq, Wk, bk, Wv, bv, Wt, bias);
    proj     <<<512, 256, 0, stream>>>(x, Wt, bias, Qrm, Krm, Vbf);
    attn     <<<512, 256, 0, stream>>>(Qrm, Krm, Vbf, Opart, Lpart);
    merge_out<<<256, 256, 0, stream>>>(Opart, Lpart, x, gamma, out);
}

// Round 10
// 175.398 us; speedup vs baseline: 1.4333x; 1.1109x over previous
//
#include <hip/hip_runtime.h>
#include <hip/hip_bf16.h>
#include <stdint.h>

// ---------------------------------------------------------------------------
// SelfAttn: B=4, W=H=64, C=256, C2=128, N=W*H=4096.
// pq = raw q buffer viewed [128,4096]  (Q_rows[n,c] = q_flat[c*4096+n])
// pv = raw v buffer viewed [256,4096]
// energy = Qrm @ Krm^T (K=128), softmax over keys (fixed ref m=0),
// O[n,c] = sum_m P[n,m] V[m,c];  final[b,c*4096+n] = gamma*O/l + x.
//
// R9 post-mortem: attn LDS traffic (104KB/CU-kt) co-dominant with MFMA; Vs
// round-trip is a layout transform only. R10: proj writes K and V PRE-PACKED
// in MFMA fragment order (Kp[c-chunk][n][16], Vp[m-chunk][c][16]) so attn
// K/V fragment loads are fully-coalesced global b128s -> Vs deleted, LDS =
// Ps only (dbuf, 1 barrier/kt). Prefetches placed so all regs single-buffered.
// ---------------------------------------------------------------------------

typedef __attribute__((ext_vector_type(8)))  short short8;   // 8 x bf16
typedef __attribute__((ext_vector_type(4)))  float f32x4;
typedef __attribute__((ext_vector_type(16))) float f32x16;
typedef __attribute__((ext_vector_type(4)))  unsigned short u16x4;

#define MFMA16 __builtin_amdgcn_mfma_f32_16x16x32_bf16
#define MFMA32 __builtin_amdgcn_mfma_f32_32x32x16_bf16

__device__ __forceinline__ unsigned short f2bf(float f) {
    union { float f; uint32_t u; } v; v.f = f;
    return (unsigned short)((v.u + 0x8000u) >> 16);    // round-half-up
}
__device__ __forceinline__ float bf2f(unsigned short h) {
    union { uint32_t u; float f; } v; v.u = ((uint32_t)h) << 16;
    return v.f;
}
// packed f32x2 -> bf16x2 (v_cvt_pk_bf16_f32, RNE)
__device__ __forceinline__ uint32_t pkbf(float a, float b) {
    union { __hip_bfloat162 h; uint32_t u; } v;
    v.h = __float22bfloat162_rn(float2{a, b});
    return v.u;
}

// --- K1: Wt[512][256] bf16 (transposed, fused qkv) + bias[512] f32 ---------
__global__ void prep_w(const float* __restrict__ Wq, const float* __restrict__ bq,
                       const float* __restrict__ Wk, const float* __restrict__ bk,
                       const float* __restrict__ Wv, const float* __restrict__ bv,
                       unsigned short* __restrict__ Wt, float* __restrict__ bias) {
    int g = blockIdx.x * 256 + threadIdx.x;
    int c = g & 255, d = g >> 8;
    float val;
    if (d < 128)      val = Wq[c * 128 + d];
    else if (d < 256) val = Wk[c * 128 + (d - 128)];
    else              val = Wv[c * 256 + (d - 256)];
    Wt[d * 256 + c] = f2bf(val);
    if (g < 512) {
        float bb;
        if (g < 128)      bb = bq[g];
        else if (g < 256) bb = bk[g - 128];
        else              bb = bv[g - 256];
        bias[g] = bb;
    }
}

// --- K2: fused QKV projection. 512 uniform blocks:
//   [0,128)   Q-kind: block(b,a) pixels {a+32*cc} -> Qrm [n][128] tiles
//   [128,256) K-kind: same pixels -> Kp[c-chunk(8)][n(4096)][k(16)] packed
//   [256,512) V-kind: block(b,vh,a) -> Vp[m-chunk(256)][c(256)][k(16)] packed
__global__ __launch_bounds__(256) void proj(
        const float* __restrict__ x, const unsigned short* __restrict__ Wt,
        const float* __restrict__ bias,
        unsigned short* __restrict__ Qrm, unsigned short* __restrict__ Kp,
        unsigned short* __restrict__ Vp) {
    __shared__ unsigned short T[128 * 136];
    int bid = blockIdx.x;
    int tid = threadIdx.x;
    int wave = tid >> 6, lane = tid & 63;
    int l16 = lane & 15, quad = lane >> 4;

    int kind, b, a, vh = 0;
    if (bid < 256) { kind = bid >> 7; int s = bid & 127; b = s >> 5; a = s & 31; }
    else           { kind = 2; int s = bid - 256; vh = s >> 7; b = (s >> 5) & 3; a = s & 31; }

    short8 af[2][8];
    #pragma unroll
    for (int g = 0; g < 2; ++g) {
        int p_local = wave * 32 + g * 16 + l16;
        int pix = (kind == 2) ? (b * 4096 + a * 128 + p_local)
                              : (b * 4096 + a + 32 * p_local);
        const float* xr = x + (size_t)pix * 256;
        #pragma unroll
        for (int kk = 0; kk < 8; ++kk) {
            f32x4 u0 = *(const f32x4*)(xr + kk * 32 + quad * 8);
            f32x4 u1 = *(const f32x4*)(xr + kk * 32 + quad * 8 + 4);
            union { short8 s; uint32_t u[4]; } h;
            h.u[0] = pkbf(u0[0], u0[1]); h.u[1] = pkbf(u0[2], u0[3]);
            h.u[2] = pkbf(u1[0], u1[1]); h.u[3] = pkbf(u1[2], u1[3]);
            af[g][kk] = h.s;
        }
    }

    if (kind < 2) {
        int dbase = kind * 128;
        #pragma unroll 1
        for (int dt = 0; dt < 8; ++dt) {
            int d = dbase + dt * 16 + l16;
            float bval = bias[d];
            f32x4 acc0 = {0.f,0.f,0.f,0.f}, acc1 = {0.f,0.f,0.f,0.f};
            #pragma unroll
            for (int kk = 0; kk < 8; ++kk) {
                short8 wrow = *(const short8*)(Wt + d * 256 + kk * 32 + quad * 8);
                acc0 = MFMA16(af[0][kk], wrow, acc0, 0, 0, 0);
                acc1 = MFMA16(af[1][kk], wrow, acc1, 0, 0, 0);
            }
            #pragma unroll
            for (int g = 0; g < 2; ++g) {
                f32x4 acc = g ? acc1 : acc0;
                union { u16x4 v; uint32_t u[2]; } pk;
                pk.u[0] = pkbf(acc[0] + bval, acc[1] + bval);
                pk.u[1] = pkbf(acc[2] + bval, acc[3] + bval);
                // T[row=d_local (-> n = a*128+d_local)][col=p_local (-> c)]
                *(u16x4*)(T + (dt * 16 + l16) * 136 + wave * 32 + g * 16 + quad * 4) = pk.v;
            }
        }
        __syncthreads();
        if (kind == 0) {
            unsigned short* ob = Qrm + (b << 19) + a * 128 * 128;
            #pragma unroll
            for (int it = 0; it < 8; ++it) {
                int ci = it * 256 + tid;
                int row = ci >> 4, cj = ci & 15;
                *(short8*)(ob + row * 128 + cj * 8) = *(const short8*)(T + row * 136 + cj * 8);
            }
        } else {
            // Kp[chunk=c>>4][n][c&15]: element (n = a*128+row, c = cj*8..+8)
            unsigned short* kb = Kp + (b << 19);
            #pragma unroll
            for (int it = 0; it < 8; ++it) {
                int ci = it * 256 + tid;
                int row = ci >> 4, cj = ci & 15;
                *(short8*)(kb + (cj >> 1) * 65536 + (a * 128 + row) * 16 + (cj & 1) * 8)
                    = *(const short8*)(T + row * 136 + cj * 8);
            }
        }
    } else {
        #pragma unroll 1
        for (int dt = 0; dt < 8; ++dt) {
            int d = 256 + vh * 128 + dt * 16 + l16;
            f32x4 acc0 = {0.f,0.f,0.f,0.f}, acc1 = {0.f,0.f,0.f,0.f};
            #pragma unroll
            for (int kk = 0; kk < 8; ++kk) {
                short8 wrow = *(const short8*)(Wt + d * 256 + kk * 32 + quad * 8);
                acc0 = MFMA16(wrow, af[0][kk], acc0, 0, 0, 0);   // A=W, B=x -> D^T
                acc1 = MFMA16(wrow, af[1][kk], acc1, 0, 0, 0);
            }
            int dvl = dt * 16 + quad * 4;
            f32x4 bv4 = *(const f32x4*)(bias + 256 + vh * 128 + dvl);
            #pragma unroll
            for (int g = 0; g < 2; ++g) {
                f32x4 acc = g ? acc1 : acc0;
                union { u16x4 v; uint32_t u[2]; } pk;
                pk.u[0] = pkbf(acc[0] + bv4[0], acc[1] + bv4[1]);
                pk.u[1] = pkbf(acc[2] + bv4[2], acc[3] + bv4[3]);
                int p_local = wave * 32 + g * 16 + l16;
                *(u16x4*)(T + p_local * 136 + dvl) = pk.v;            // T[p][dvl]
            }
        }
        __syncthreads();
        // element (p, dv): c = p>>4 (+a*8), m = (p&15)*256 + vh*128 + dv
        // Vp[chunk = m>>4][c][m&15]; m&15 = dv&15
        unsigned short* vb = Vp + (b << 20);
        #pragma unroll
        for (int it = 0; it < 8; ++it) {
            int cid = it * 256 + tid;
            int c_local = cid >> 8, w = cid & 255;       // p&15 = w>>4, dvl8 = w&15
            int p_local = c_local * 16 + (w >> 4);
            int chunk = (w >> 4) * 16 + vh * 8 + ((w & 15) >> 1);
            *(short8*)(vb + chunk * 4096 + (a * 8 + c_local) * 16 + (w & 1) * 8)
                = *(const short8*)(T + p_local * 136 + (w & 15) * 8);
        }
    }
}

// --- K3: flash attention. grid 512 = 64 qtiles x (4 b x 2 ks) --------------
// 64 queries/block, 64-key tiles (32 tiles), 32x32x16 MFMA.
// K/V fragments loaded DIRECT from packed global layouts (coalesced b128),
// single-buffered regs (prefetch placed after consumption point).
// LDS = Ps only, double-buffered -> 1 barrier/kt.
__global__ __launch_bounds__(256, 2) void attn(
        const unsigned short* __restrict__ Qrm, const unsigned short* __restrict__ Kp,
        const unsigned short* __restrict__ Vp, unsigned short* __restrict__ Opart,
        float* __restrict__ Lpart) {
    __shared__ unsigned short Ps[2 * 64 * 72];         // P [q=64][m=64 +pad], x2

    int bid = blockIdx.x;
    int comb = bid & 7, qt = bid >> 3;                 // same (b,ks) -> same XCD
    int b = comb >> 1, ks = comb & 1;
    int tid = threadIdx.x, wave = tid >> 6, lane = tid & 63;
    int l32 = lane & 31, half = lane >> 5;
    int mt = wave & 1, nt = wave >> 1;

    const unsigned short* Qb = Qrm + (b << 19);
    const unsigned short* Kb = Kp + (b << 19);
    const unsigned short* Vb = Vp + (b << 20);

    int q0 = qt * 64;

    short8 qf[8];                                      // B=Q for wave's 32 queries
    {
        const unsigned short* qrow = Qb + (q0 + nt * 32 + l32) * 128 + half * 8;
        #pragma unroll
        for (int kk = 0; kk < 8; ++kk) qf[kk] = *(const short8*)(qrow + kk * 16);
    }

    f32x16 O[2][2];                                    // [qtile][ctile]
    #pragma unroll
    for (int i = 0; i < 2; ++i)
        #pragma unroll
        for (int j = 0; j < 2; ++j)
            #pragma unroll
            for (int r = 0; r < 16; ++r) O[i][j][r] = 0.f;
    float l_run = 0.f;                                 // own-half partial only

    const int m_base = ks * 2048;
    const int chunk_base = ks * 128;                   // m_base>>4

    // tile-0 fragments (coalesced packed loads)
    int krow = (m_base + mt * 32 + l32) * 16 + half * 8;
    short8 kf[8];
    #pragma unroll
    for (int kk = 0; kk < 8; ++kk)
        kf[kk] = *(const short8*)(Kb + kk * 65536 + krow);
    short8 vfrag[2][4];
    #pragma unroll
    for (int c2 = 0; c2 < 2; ++c2)
        #pragma unroll
        for (int k2 = 0; k2 < 4; ++k2)
            vfrag[c2][k2] = *(const short8*)(Vb + (chunk_base + k2) * 4096
                              + ((wave * 2 + c2) * 32 + l32) * 16 + half * 8);

    #pragma unroll 1
    for (int kt = 0; kt < 32; ++kt) {
        unsigned short* Pb = Ps + (kt & 1) * (64 * 72);

        // 1. S^T[m][n]: A=kf (keys), B=qf (queries); col n = l32 (query),
        //    row m (within mtile) = (r&3)+8*(r>>2)+4*half.
        f32x16 S;
        #pragma unroll
        for (int r = 0; r < 16; ++r) S[r] = 0.f;
        #pragma unroll
        for (int kk = 0; kk < 8; ++kk) S = MFMA32(kf[kk], qf[kk], S, 0, 0, 0);

        // 2. fixed-ref softmax (m=0): p = exp(S); pack -> Ps[buf]
        #pragma unroll
        for (int g = 0; g < 4; ++g) {
            float p0 = __expf(S[g * 4 + 0]), p1 = __expf(S[g * 4 + 1]);
            float p2 = __expf(S[g * 4 + 2]), p3 = __expf(S[g * 4 + 3]);
            l_run += (p0 + p1) + (p2 + p3);
            union { u16x4 v; uint32_t u[2]; } pk;
            pk.u[0] = pkbf(p0, p1); pk.u[1] = pkbf(p2, p3);
            // P[q][m]: q = nt*32+l32, m = mt*32 + g*8 + half*4 + i
            *(u16x4*)(Pb + (nt * 32 + l32) * 72 + mt * 32 + g * 8 + half * 4) = pk.v;
        }

        __syncthreads();                               // 3. Ps[buf] ready

        if (kt < 31) {                                 // 4. kf prefetch (kf consumed in 1)
            int kr1 = (m_base + (kt + 1) * 64 + mt * 32 + l32) * 16 + half * 8;
            #pragma unroll
            for (int kk = 0; kk < 8; ++kk)
                kf[kk] = *(const short8*)(Kb + kk * 65536 + kr1);
        }

        // 5. PV: A = P rows (q), B = vfrag; wave ctiles {2w,2w+1}, qtiles {0,1}
        #pragma unroll
        for (int k2 = 0; k2 < 4; ++k2) {
            short8 pa0 = *(const short8*)(Pb + (l32) * 72 + k2 * 16 + half * 8);
            short8 pa1 = *(const short8*)(Pb + (32 + l32) * 72 + k2 * 16 + half * 8);
            O[0][0] = MFMA32(pa0, vfrag[0][k2], O[0][0], 0, 0, 0);
            O[0][1] = MFMA32(pa0, vfrag[1][k2], O[0][1], 0, 0, 0);
            O[1][0] = MFMA32(pa1, vfrag[0][k2], O[1][0], 0, 0, 0);
            O[1][1] = MFMA32(pa1, vfrag[1][k2], O[1][1], 0, 0, 0);
        }

        if (kt < 31) {                                 // 6. vfrag prefetch (consumed in 5)
            int ch1 = chunk_base + (kt + 1) * 4;
            #pragma unroll
            for (int c2 = 0; c2 < 2; ++c2)
                #pragma unroll
                for (int k2 = 0; k2 < 4; ++k2)
                    vfrag[c2][k2] = *(const short8*)(Vb + (ch1 + k2) * 4096
                                      + ((wave * 2 + c2) * 32 + l32) * 16 + half * 8);
        }
    }

    // epilogue: unnormalized O + per-query l partials (cross-half sum here)
    l_run += __shfl_xor(l_run, 32);
    unsigned short* Op = Opart + ((size_t)(ks * 4 + b) << 20);
    #pragma unroll
    for (int q2 = 0; q2 < 2; ++q2)
        #pragma unroll
        for (int c2 = 0; c2 < 2; ++c2) {
            int c = (wave * 2 + c2) * 32 + l32;
            #pragma unroll
            for (int r = 0; r < 16; ++r) {
                int n = q0 + q2 * 32 + (r & 3) + 8 * (r >> 2) + 4 * half;
                Op[(size_t)n * 256 + c] = f2bf(O[q2][c2][r]);
            }
        }
    if (half == 0) {
        int n = q0 + nt * 32 + l32;
        Lpart[((ks * 2 + mt) * 4 + b) * 4096 + n] = l_run;
    }
}

// --- K4: merge 2 key-splits, gamma*O/l + x, transpose [n,c]->[c,n] ---------
// Vectorized: short8 Opart reads, f32x4 out/x. 256 blocks (b, n-tile of 64).
__global__ __launch_bounds__(256) void merge_out(
        const unsigned short* __restrict__ Opart, const float* __restrict__ Lpart,
        const float* __restrict__ x, const float* __restrict__ gamma,
        float* __restrict__ out) {
    __shared__ float tile[64 * 257];                   // [n=64][c=256 +pad]
    __shared__ float wsm[64];
    int b  = blockIdx.x >> 6;
    int n0 = (blockIdx.x & 63) << 6;
    int tid = threadIdx.x;
    float g = gamma[0];
    if (tid < 64) {
        int n = n0 + tid;
        float L = 0.f;
        #pragma unroll
        for (int s = 0; s < 4; ++s) L += Lpart[(s * 4 + b) * 4096 + n];
        wsm[tid] = g / L;
    }
    __syncthreads();
    // phase 1: 8 iters, thread -> (n = i*8 + tid>>5, c = (tid&31)*8 .. +8)
    int nl1 = tid >> 5, cb1 = (tid & 31) * 8;
    const unsigned short* Op0 = Opart + ((size_t)(0 * 4 + b) << 20);
    const unsigned short* Op1 = Opart + ((size_t)(1 * 4 + b) << 20);
    #pragma unroll
    for (int i = 0; i < 8; ++i) {
        int nl = i * 8 + nl1;
        size_t off = (size_t)(n0 + nl) * 256 + cb1;
        short8 o0 = *(const short8*)(Op0 + off);
        short8 o1 = *(const short8*)(Op1 + off);
        float w = wsm[nl];
        float* tr = tile + nl * 257 + cb1;
        #pragma unroll
        for (int e = 0; e < 8; ++e)
            tr[e] = (bf2f((unsigned short)o0[e]) + bf2f((unsigned short)o1[e])) * w;
    }
    __syncthreads();
    // phase 2: 16 iters, thread -> (c = it*16 + tid>>4, n = (tid&15)*4 .. +4)
    int cg = tid >> 4, nq = (tid & 15) * 4;
    #pragma unroll
    for (int it = 0; it < 16; ++it) {
        int c = it * 16 + cg;
        size_t idx = ((size_t)b << 20) + (size_t)c * 4096 + n0 + nq;
        f32x4 xv = *(const f32x4*)(x + idx);
        f32x4 ov;
        #pragma unroll
        for (int e = 0; e < 4; ++e) ov[e] = tile[(nq + e) * 257 + c] + xv[e];
        *(f32x4*)(out + idx) = ov;
    }
}

// ---------------------------------------------------------------------------
extern "C" void kernel_launch(void* const* d_in, const int* in_sizes, int n_in,
                              void* d_out, int out_size, void* d_ws, size_t ws_size,
                              hipStream_t stream) {
    const float* x     = (const float*)d_in[0];
    const float* Wq    = (const float*)d_in[1];
    const float* bq    = (const float*)d_in[2];
    const float* Wk    = (const float*)d_in[3];
    const float* bk    = (const float*)d_in[4];
    const float* Wv    = (const float*)d_in[5];
    const float* bv    = (const float*)d_in[6];
    const float* gamma = (const float*)d_in[7];
    float* out = (float*)d_out;

    if (ws_size < 34080768u) return;   // need ~33 MB scratch

    char* ws = (char*)d_ws;
    unsigned short* Wt    = (unsigned short*)(ws);             //    262,144 B
    float*          bias  = (float*)        (ws +   262144);   //      2,048 B
    unsigned short* Qrm   = (unsigned short*)(ws +   264192);  //  4,194,304 B
    unsigned short* Kp    = (unsigned short*)(ws +  4458496);  //  4,194,304 B
    unsigned short* Vp    = (unsigned short*)(ws +  8652800);  //  8,388,608 B
    unsigned short* Opart = (unsigned short*)(ws + 17041408);  // 16,777,216 B
    float*          Lpart = (float*)        (ws + 33818624);   //    262,144 B

    prep_w   <<<512, 256, 0, stream>>>(Wq, bq, Wk, bk, Wv, bv, Wt, bias);
    proj     <<<512, 256, 0, stream>>>(x, Wt, bias, Qrm, Kp, Vp);
    attn     <<<512, 256, 0, stream>>>(Qrm, Kp, Vp, Opart, Lpart);
    merge_out<<<256, 256, 0, stream>>>(Opart, Lpart, x, gamma, out);
}